// Round 6
// baseline (292.592 us; speedup 1.0000x reference)
//
#include <hip/hip_runtime.h>

#define KS     11
#define HH     512
#define WW     512
#define OUTD   502         // HH - KS + 1
#define OH     67          // output rows per band
#define ROWS   77          // OH + KS - 1 = 7*11 (multiple of KS)
#define NBANDS 8           // 8*67 = 536 >= 502
#define ECOLS  52          // emitted cols per wave (64 staged - 12 halo)
#define NSTRIP 10          // 10*52 = 520 >= 502
#define NIMG   96          // N*C = 32*3
#define NACC   256         // max accumulator slots (used only if workspace fits)

// Pair-split shuffle SSIM (no LDS, no barriers), sum/difference form:
//   s = x+y, d = x-y; 4 convolved quantities {s, d, s^2, d^2}:
//     4 mu_x mu_y = ms^2-md^2   2(mu_x^2+mu_y^2) = ms^2+md^2
//     4 conv(xy)  = Sss-Sdd     2(conv x^2+y^2)  = Sss+Sdd
//   (factors fold into doubled constants; absmax 0.0 verified R1/R2/R4/R5).
//
// R5 post-mortem: VGPR=64, no LDS, but dur 153us at Occupancy 35% -- the
// grid (3840 waves = 3.75/SIMD) was the limiter, and the measured
// "VALUBusy 69%" is ~2x-inflated by the gfx94x SIMD-16 fallback formula;
// real issue time ~60us -> latency-bound. Fixes:
//  (1) NBANDS 4->8: 7680 single-wave blocks = 7.5 waves/SIMD (VGPR 64
//      permits 8) for 2x latency hiding, at +7.7% staged-row overhead.
//  (2) each lane loads BOTH x,y (partner bytes are L1 hits) and forms
//      v = x +/- y locally: removes the 2 shfl_xor partner exchange from
//      the head of every row's dependency chain.
__global__ __launch_bounds__(64, 4)
void ssim_main(const float* __restrict__ xg, const float* __restrict__ yg,
               const float* __restrict__ win, double* __restrict__ acc_out,
               const int accmask)
{
    const int lane   = threadIdx.x;           // 0..63
    const int bid    = blockIdx.x;
    const int strip  = bid % NSTRIP;
    const int band   = (bid / NSTRIP) % NBANDS;
    const int img    = bid / (NSTRIP * NBANDS);
    const int row0   = band * OH;
    const int parity = lane & 1;

    // Recover 1D gaussian from the (normalized, rank-1) 2D window: row sums.
    // Symmetric: store g[0..5], fold index at compile time.
    float g[6];
    #pragma unroll
    for (int i = 0; i < 6; i++) {
        float s = 0.f;
        #pragma unroll
        for (int j = 0; j < KS; j++) s += win[i * KS + j];
        g[i] = s;
    }
#define G(j) g[(j) <= 5 ? (j) : 10 - (j)]

    // Pair p = lane>>1 owns staged cols (2p, 2p+1); lane loads BOTH x and y
    // there (pair partner reads the same bytes -> L1 hit) and forms its own
    // quantity locally: even lane v = x+y (s), odd lane v = x-y (d).
    int gcol = ECOLS * strip + (lane & ~1);
    if (gcol > WW - 2) gcol = WW - 2;         // strip 9 tail: clamp, finite garbage, gated
    const float* xp = xg + (size_t)img * (HH * WW) + gcol;
    const float* yp = yg + (size_t)img * (HH * WW) + gcol;
    const float sgn = parity ? -1.f : 1.f;    // v = fmaf(sgn, y, x)

    // rotating vertical accumulators [q: 0=v, 1=v^2][col][slot] -- 44 floats.
    // Slot emitted at row r is overwritten (mul) at row r+1 -> no reset pass.
    float acc[2][2][KS];
    #pragma unroll
    for (int q = 0; q < 2; q++)
        #pragma unroll
        for (int c = 0; c < 2; c++)
            #pragma unroll
            for (int s = 0; s < KS; s++) acc[q][c][s] = 0.f;

    float ssum = 0.f;
    const float C1x2 = 0.0002f;  // 2*(0.01)^2
    const float C2x2 = 0.0018f;  // 2*(0.03)^2

    // prefetch row0 (depth-1; 30 waves/CU TLP hides the rest)
    float2 pfx = *(const float2*)(xp + (size_t)row0 * WW);
    float2 pfy = *(const float2*)(yp + (size_t)row0 * WW);

    #pragma unroll 1
    for (int rb = 0; rb < ROWS / KS; rb++) {
        #pragma unroll
        for (int rr = 0; rr < KS; rr++) {
            const int r = rb * KS + rr;

            // consume prefetched row r; issue loads for row r+1 immediately
            const float2 cx = pfx, cy = pfy;
            {
                int gr = row0 + r + 1; if (gr > HH - 1) gr = HH - 1;
                pfx = *(const float2*)(xp + (size_t)gr * WW);
                pfy = *(const float2*)(yp + (size_t)gr * WW);
            }

            // local quantity formation (no cross-lane dependency)
            const float v0 = fmaf(sgn, cy.x, cx.x);
            const float v1 = fmaf(sgn, cy.y, cx.y);

            // halo gather: staged cols 2p..2p+11 of own quantity via shfl_down
            float sv[12];
            sv[0] = v0; sv[1] = v1;
            #pragma unroll
            for (int k = 1; k <= 5; k++) {
                sv[2 * k]     = __shfl_down(v0, 2 * k);
                sv[2 * k + 1] = __shfl_down(v1, 2 * k);
            }

            // horizontal 11-tap conv of {v, v^2} for 2 cols (rolling square)
            float hv0 = 0.f, hv1 = 0.f, hq0 = 0.f, hq1 = 0.f;
            float q0 = sv[0] * sv[0];
            #pragma unroll
            for (int j = 0; j < KS; j++) {
                const float gj = G(j);
                const float q1 = sv[j + 1] * sv[j + 1];
                hv0 = fmaf(gj, sv[j],     hv0);
                hv1 = fmaf(gj, sv[j + 1], hv1);
                hq0 = fmaf(gj, q0,        hq0);
                hq1 = fmaf(gj, q1,        hq1);
                q0 = q1;
            }

            // vertical accumulate; i==0 targets slot rr (emitted last row): overwrite
            {
                const float g0 = G(0);
                acc[0][0][rr] = g0 * hv0; acc[0][1][rr] = g0 * hv1;
                acc[1][0][rr] = g0 * hq0; acc[1][1][rr] = g0 * hq1;
            }
            #pragma unroll
            for (int i = 1; i < KS; i++) {
                const int slot = (rr - i + KS) % KS;
                const float gi = G(i);
                acc[0][0][slot] = fmaf(gi, hv0, acc[0][0][slot]);
                acc[0][1][slot] = fmaf(gi, hv1, acc[0][1][slot]);
                acc[1][0][slot] = fmaf(gi, hq0, acc[1][0][slot]);
                acc[1][1][slot] = fmaf(gi, hq1, acc[1][1][slot]);
            }

            // emit completed output row jloc = r-10 (slot (rr+1)%11).
            // Lane emits ONE col: ecol = strip base + lane. All gates are
            // pair-uniform (ECOLS even; ecol<OUTD can only split between
            // pairs since strip base is even), so the shfl_xor pairs below
            // always have both partners active.
            const int es   = (rr + 1) % KS;
            const int jloc = r - (KS - 1);
            const int ecol = ECOLS * strip + lane;
            if (jloc >= 0 && jloc < OH && (row0 + jloc) < OUTD &&
                lane < ECOLS && ecol < OUTD) {
                // reunite quantities: even lane has (ms,Ss) pair, odd has (md,Sd)
                const float pm0 = __shfl_xor(acc[0][0][es], 1);
                const float pm1 = __shfl_xor(acc[0][1][es], 1);
                const float pS0 = __shfl_xor(acc[1][0][es], 1);
                const float pS1 = __shfl_xor(acc[1][1][es], 1);
                const float ms = parity ? pm1 : acc[0][0][es];
                const float md = parity ? acc[0][1][es] : pm0;
                const float Ss = parity ? pS1 : acc[1][0][es];
                const float Sd = parity ? acc[1][1][es] : pS0;
                const float a = ms * ms, b = md * md;
                const float P = a - b;        // 4 mu_x mu_y
                const float Q = a + b;        // 2(mu_x^2 + mu_y^2)
                const float U = Ss - Sd;      // 4 conv(xy)
                const float V = Ss + Sd;      // 2(conv x^2 + conv y^2)
                const float num = (P + C1x2) * ((U - P) + C2x2);
                const float den = (Q + C1x2) * ((V - Q) + C2x2);
                float rc = __builtin_amdgcn_rcpf(den);
                rc = rc * fmaf(-den, rc, 2.0f);   // one NR step: ~0.5 ulp
                ssum = fmaf(num, rc, ssum);
            }
        }
    }

    // single-wave block: shuffle reduce, one atomic into a spread slot
    #pragma unroll
    for (int off = 32; off > 0; off >>= 1)
        ssum += __shfl_down(ssum, off);
    if (lane == 0)
        atomicAdd(&acc_out[bid & accmask], (double)ssum);
}

__global__ void ssim_finalize(const double* __restrict__ acc, float* __restrict__ out,
                              const int nacc)
{
    double s = 0.0;
    for (int i = threadIdx.x; i < nacc; i += 64) s += acc[i];
    #pragma unroll
    for (int off = 32; off > 0; off >>= 1)
        s += __shfl_down(s, off);
    if (threadIdx.x == 0)
        out[0] = (float)(s * (1.0 / 24192384.0));   // 96*502*502 outputs
}

extern "C" void kernel_launch(void* const* d_in, const int* in_sizes, int n_in,
                              void* d_out, int out_size, void* d_ws, size_t ws_size,
                              hipStream_t stream)
{
    const float* x   = (const float*)d_in[0];
    const float* y   = (const float*)d_in[1];
    const float* win = (const float*)d_in[2];
    float* out = (float*)d_out;
    double* acc = (double*)d_ws;

    // Never assume workspace size (R3 lesson): spread slots only if they fit.
    const int nacc = (ws_size >= NACC * sizeof(double)) ? NACC : 1;
    hipMemsetAsync(acc, 0, nacc * sizeof(double), stream);
    ssim_main<<<dim3(NIMG * NBANDS * NSTRIP), dim3(64), 0, stream>>>(
        x, y, win, acc, nacc - 1);
    ssim_finalize<<<dim3(1), dim3(64), 0, stream>>>(acc, out, nacc);
}